// Round 3
// baseline (88.133 us; speedup 1.0000x reference)
//
#include <hip/hip_runtime.h>

// Integrate-and-fire over T=4 timesteps, fp32.
// x viewed as [T, S] with S = B*C*H*W. Each thread owns 2 consecutive
// 16-byte vectors (32 B) of the spatial axis, scans t=0..3 with mem in
// registers:  mem += x_t; spike = (mem >= thre) ? thre : 0; mem -= spike
// All 8 loads issued before compute (latency hiding); stores are
// non-temporal (nt) so the 205 MB output stream does not evict x from
// the 256 MB Infinity Cache (x is re-read every replay and L3-fits).

typedef float vfloat4 __attribute__((ext_vector_type(4)));

#define IF_STEP(m, xv, sv) { (m) += (xv); (sv) = ((m) >= thre) ? thre : 0.0f; (m) -= (sv); }

__global__ __launch_bounds__(256) void if_scan_kernel(
    const float* __restrict__ x,
    const float* __restrict__ thresh,
    float* __restrict__ out,
    long long n4,        // vfloat4 count per timestep slab = S/4
    long long n8)        // pair count = n4/2
{
    const float thre = thresh[0];
    const float half = 0.5f * thre;
    const long long s = n4;  // timestep stride in vfloat4 units

    const vfloat4* __restrict__ x4 = reinterpret_cast<const vfloat4*>(x);
    vfloat4* __restrict__ o4 = reinterpret_cast<vfloat4*>(out);

    const long long gsz = (long long)gridDim.x * blockDim.x;
    long long j = (long long)blockIdx.x * blockDim.x + threadIdx.x;

    for (; j < n8; j += gsz) {
        const long long i = 2 * j;
        // issue all 8 loads up front
        vfloat4 xa0 = x4[i + 0 * s], xb0 = x4[i + 1 + 0 * s];
        vfloat4 xa1 = x4[i + 1 * s], xb1 = x4[i + 1 + 1 * s];
        vfloat4 xa2 = x4[i + 2 * s], xb2 = x4[i + 2 * s + 1];
        vfloat4 xa3 = x4[i + 3 * s], xb3 = x4[i + 3 * s + 1];

        vfloat4 sa0, sa1, sa2, sa3, sb0, sb1, sb2, sb3;
        {
            float m;
            #pragma unroll
            for (int c = 0; c < 4; ++c) {
                m = half;
                IF_STEP(m, xa0[c], sa0[c]); IF_STEP(m, xa1[c], sa1[c]);
                IF_STEP(m, xa2[c], sa2[c]); IF_STEP(m, xa3[c], sa3[c]);
                m = half;
                IF_STEP(m, xb0[c], sb0[c]); IF_STEP(m, xb1[c], sb1[c]);
                IF_STEP(m, xb2[c], sb2[c]); IF_STEP(m, xb3[c], sb3[c]);
            }
        }

        __builtin_nontemporal_store(sa0, &o4[i + 0 * s]);
        __builtin_nontemporal_store(sb0, &o4[i + 0 * s + 1]);
        __builtin_nontemporal_store(sa1, &o4[i + 1 * s]);
        __builtin_nontemporal_store(sb1, &o4[i + 1 * s + 1]);
        __builtin_nontemporal_store(sa2, &o4[i + 2 * s]);
        __builtin_nontemporal_store(sb2, &o4[i + 2 * s + 1]);
        __builtin_nontemporal_store(sa3, &o4[i + 3 * s]);
        __builtin_nontemporal_store(sb3, &o4[i + 3 * s + 1]);
    }

    // tail: if n4 is odd, the last vector of each slab is unpaired
    if ((n4 & 1) && (blockIdx.x == 0) && (threadIdx.x == 0)) {
        const long long i = n4 - 1;
        vfloat4 x0 = x4[i + 0 * s], x1 = x4[i + 1 * s];
        vfloat4 x2 = x4[i + 2 * s], x3 = x4[i + 3 * s];
        vfloat4 s0, s1, s2, s3;
        float m;
        #pragma unroll
        for (int c = 0; c < 4; ++c) {
            m = half;
            IF_STEP(m, x0[c], s0[c]); IF_STEP(m, x1[c], s1[c]);
            IF_STEP(m, x2[c], s2[c]); IF_STEP(m, x3[c], s3[c]);
        }
        __builtin_nontemporal_store(s0, &o4[i + 0 * s]);
        __builtin_nontemporal_store(s1, &o4[i + 1 * s]);
        __builtin_nontemporal_store(s2, &o4[i + 2 * s]);
        __builtin_nontemporal_store(s3, &o4[i + 3 * s]);
    }
}

extern "C" void kernel_launch(void* const* d_in, const int* in_sizes, int n_in,
                              void* d_out, int out_size, void* d_ws, size_t ws_size,
                              hipStream_t stream) {
    const float* x = (const float*)d_in[0];
    const float* thresh = (const float*)d_in[1];
    float* out = (float*)d_out;

    const long long n_total = (long long)in_sizes[0];  // T * B * C * H * W
    const int T = 4;
    const long long n_spatial = n_total / T;           // B*C*H*W
    const long long n4 = n_spatial / 4;                // 16B vectors per slab
    const long long n8 = n4 / 2;                       // vector-pairs per slab

    const int block = 256;
    long long blocks_needed = (n8 + block - 1) / block;
    int grid = (int)((blocks_needed < 2048) ? blocks_needed : 2048);
    if (grid < 1) grid = 1;

    if_scan_kernel<<<grid, block, 0, stream>>>(x, thresh, out, n4, n8);
}

// Round 4
// 63.073 us; speedup vs baseline: 1.3973x; 1.3973x over previous
//
#include <hip/hip_runtime.h>

// Integrate-and-fire over T=4 timesteps, fp32.
// x viewed as [T, S], S = B*C*H*W. Thread j owns vec4 index j of the
// spatial axis (unit lane stride -> each wave store covers a contiguous
// 1KB segment), scans t=0..3 with mem in registers:
//   mem += x_t; spike = (mem >= thre) ? thre : 0; mem -= spike
// Stores are non-temporal so the 205 MB output stream does not evict x
// from the 256 MB Infinity Cache (x is re-read every replay; R3 showed
// FETCH_SIZE 205->101 MB from this). R3's 2-vec4-per-thread pairing
// broke store coalescing (32B lane stride -> WRITE_SIZE 242 MB for a
// 205 MB output); reverted to unit stride here.

typedef float vfloat4 __attribute__((ext_vector_type(4)));

#define IF_STEP(m, xv, sv) { (m) += (xv); (sv) = ((m) >= thre) ? thre : 0.0f; (m) -= (sv); }

__global__ __launch_bounds__(256) void if_scan_kernel(
    const float* __restrict__ x,
    const float* __restrict__ thresh,
    float* __restrict__ out,
    long long n4)        // vec4 count per timestep slab = S/4
{
    const float thre = thresh[0];
    const float half = 0.5f * thre;
    const long long s = n4;  // timestep stride in vec4 units

    const vfloat4* __restrict__ x4 = reinterpret_cast<const vfloat4*>(x);
    vfloat4* __restrict__ o4 = reinterpret_cast<vfloat4*>(out);

    const long long gsz = (long long)gridDim.x * blockDim.x;
    long long i = (long long)blockIdx.x * blockDim.x + threadIdx.x;

    for (; i < n4; i += gsz) {
        // 4 independent loads issued up front
        vfloat4 x0 = x4[i + 0 * s];
        vfloat4 x1 = x4[i + 1 * s];
        vfloat4 x2 = x4[i + 2 * s];
        vfloat4 x3 = x4[i + 3 * s];

        vfloat4 s0, s1, s2, s3;
        #pragma unroll
        for (int c = 0; c < 4; ++c) {
            float m = half;
            IF_STEP(m, x0[c], s0[c]);
            IF_STEP(m, x1[c], s1[c]);
            IF_STEP(m, x2[c], s2[c]);
            IF_STEP(m, x3[c], s3[c]);
        }

        __builtin_nontemporal_store(s0, &o4[i + 0 * s]);
        __builtin_nontemporal_store(s1, &o4[i + 1 * s]);
        __builtin_nontemporal_store(s2, &o4[i + 2 * s]);
        __builtin_nontemporal_store(s3, &o4[i + 3 * s]);
    }
}

extern "C" void kernel_launch(void* const* d_in, const int* in_sizes, int n_in,
                              void* d_out, int out_size, void* d_ws, size_t ws_size,
                              hipStream_t stream) {
    const float* x = (const float*)d_in[0];
    const float* thresh = (const float*)d_in[1];
    float* out = (float*)d_out;

    const long long n_total = (long long)in_sizes[0];  // T * B * C * H * W
    const int T = 4;
    const long long n_spatial = n_total / T;           // B*C*H*W
    const long long n4 = n_spatial / 4;                // vec4 per slab

    const int block = 256;
    long long blocks_needed = (n4 + block - 1) / block;
    int grid = (int)((blocks_needed < 2048) ? blocks_needed : 2048);
    if (grid < 1) grid = 1;

    if_scan_kernel<<<grid, block, 0, stream>>>(x, thresh, out, n4);
}